// Round 2
// baseline (456.048 us; speedup 1.0000x reference)
//
#include <hip/hip_runtime.h>

using u16 = unsigned short;
typedef __attribute__((ext_vector_type(8))) _Float16 h8v;  // fp16x8 MFMA fragment (4 VGPRs)
typedef __attribute__((ext_vector_type(8))) u16 us8;       // raw 16B move
typedef __attribute__((ext_vector_type(4))) float f4v;     // fp32x4 accumulator

// ---------- helpers ----------
__device__ __forceinline__ u16 f2h(float f) {
  _Float16 h = (_Float16)f;                 // v_cvt_f16_f32, RNE
  return __builtin_bit_cast(unsigned short, h);
}
__device__ __forceinline__ _Float16 bits2h(u16 u) {
  return __builtin_bit_cast(_Float16, u);
}

__device__ __forceinline__ f4v mfma16(h8v a, h8v b, f4v c) {
  return __builtin_amdgcn_mfma_f32_16x16x32_f16(a, b, c, 0, 0, 0);
}

__device__ __forceinline__ void gll16(const void* g, void* l) {
  __builtin_amdgcn_global_load_lds(
      (const __attribute__((address_space(1))) void*)g,
      (__attribute__((address_space(3))) void*)l, 16, 0, 0);
}

// Problem constants
// B=16, C=512, W=64, H=64, OUT=512, NH=8, HD=64, hd2=32, seq K=64
// qkv_ws layout: [s=(b*64+h)][w][o 0..1024) fp16 ; attn_ws: [s][w][C 0..512) fp16

// ---------- setup: fp16 weight copies + gathered/transposed emb tables ----------
__global__ __launch_bounds__(256) void k0_setup(
    const float* __restrict__ w1, const float* __restrict__ wout,
    const float* __restrict__ rel, u16* __restrict__ W1b, u16* __restrict__ Woutb,
    u16* __restrict__ EqT, u16* __restrict__ EkT, u16* __restrict__ Evp)
{
  int idx = blockIdx.x * 256 + threadIdx.x;
  if (idx < 524288) {                       // W1b [1024][512]
    W1b[idx] = f2h(w1[idx]);
  } else if (idx < 786432) {                // Woutb [512][512]
    int k = idx - 524288; Woutb[k] = f2h(wout[k]);
  } else if (idx < 790528) {                // EqT [t 128][c 32] = rel[c][t]
    int k = idx - 786432; int t = k >> 5, c = k & 31;
    EqT[k] = (t < 127) ? f2h(rel[c * 127 + t]) : (u16)0;
  } else if (idx < 794624) {                // EkT [t 128][c 32] = rel[32+c][t]
    int k = idx - 790528; int t = k >> 5, c = k & 31;
    EkT[k] = (t < 127) ? f2h(rel[(32 + c) * 127 + t]) : (u16)0;
  } else if (idx < 802816) {                // Evp [c 64][t 128] = rel[64+c][t]
    int k = idx - 794624; int c = k >> 7, t = k & 127;
    Evp[k] = (t < 127) ? f2h(rel[(64 + c) * 127 + t]) : (u16)0;
  }
}

// ---------- K1: qkv = x-rows @ W1^T + b, D[m=o][n=r], epilogue transpose ----------
__global__ __launch_bounds__(256) void k1_qkv(
    const float* __restrict__ x, const u16* __restrict__ W1b,
    const float* __restrict__ bias, u16* __restrict__ qkv)
{
  const int bid = blockIdx.x;
  const int rt = bid & 511, ot = bid >> 9;      // same x-tile -> same XCD
  const int b = rt >> 5;
  const int w0 = (rt & 31) * 2;
  const int o0 = ot * 128;
  const int tid = threadIdx.x;
  const int l = tid & 63, wv = tid >> 6;
  const int lr = l & 15, lg = l >> 4;
  const int osub = (wv & 1) * 64, rsub = (wv >> 1) * 64;

  __shared__ u16 POOL[16384];        // 32KB: A dbuf @0 (2*4096), B dbuf @8192 ; Tr reuses all
  u16* Al = POOL;
  u16* Bl = POOL + 8192;

  f4v acc[4][4];
#pragma unroll
  for (int i = 0; i < 4; i++)
#pragma unroll
    for (int j = 0; j < 4; j++) acc[i][j] = (f4v){0.f, 0.f, 0.f, 0.f};

  const float* xb = x + (size_t)b * 512 * 64 * 64;

  // A-stage (W1b rows, source-swizzled so frag reads are conflict-light)
  auto stageA = [&](int kk, int buf) {
    int c0 = kk * 32;
#pragma unroll
    for (int q = 0; q < 2; q++) {
      int inst = wv * 2 + q;
      int o_l = inst * 16 + (l >> 2);
      int p = l & 3;
      int sc = p ^ ((o_l >> 2) & 3);
      const u16* src = W1b + (size_t)(o0 + o_l) * 512 + c0 + sc * 8;
      gll16(src, Al + buf * 4096 + inst * 512);
    }
  };
  auto loadX = [&](int kk, float4* vx) {
    int c0 = kk * 32;
#pragma unroll
    for (int k4 = 0; k4 < 4; k4++) {
      int pair = (tid >> 4) + k4 * 16;
      int c_l = pair & 31, w_l = pair >> 5;
      vx[k4] = *(const float4*)&xb[(((size_t)(c0 + c_l)) * 64 + (w0 + w_l)) * 64 + (tid & 15) * 4];
    }
  };
  auto writeX = [&](const float4* vx, int buf) {
#pragma unroll
    for (int k4 = 0; k4 < 4; k4++) {
      int pair = (tid >> 4) + k4 * 16;
      int c_l = pair & 31, w_l = pair >> 5;
      int hbase = (tid & 15) * 4;
      float vals[4] = {vx[k4].x, vx[k4].y, vx[k4].z, vx[k4].w};
#pragma unroll
      for (int e = 0; e < 4; e++) {
        int r_l = w_l * 64 + hbase + e;
        Bl[buf * 4096 + r_l * 32 + (((c_l >> 3) ^ ((r_l >> 2) & 3)) << 3) + (c_l & 7)] =
            f2h(vals[e]);
      }
    }
  };

  float4 vx[4];
  loadX(0, vx);
  stageA(0, 0);
  writeX(vx, 0);
  __syncthreads();

  for (int kk = 0; kk < 16; kk++) {
    int cur = kk & 1, nxt = cur ^ 1;
    if (kk < 15) { loadX(kk + 1, vx); stageA(kk + 1, nxt); }
    h8v af[4], bfr[4];
#pragma unroll
    for (int mt = 0; mt < 4; mt++) {
      int o_l = osub + mt * 16 + lr;
      af[mt] = *(const h8v*)&Al[cur * 4096 + o_l * 32 + ((lg ^ ((o_l >> 2) & 3)) << 3)];
    }
#pragma unroll
    for (int nt = 0; nt < 4; nt++) {
      int r_l = rsub + nt * 16 + lr;
      bfr[nt] = *(const h8v*)&Bl[cur * 4096 + r_l * 32 + ((lg ^ ((r_l >> 2) & 3)) << 3)];
    }
#pragma unroll
    for (int mt = 0; mt < 4; mt++)
#pragma unroll
      for (int nt = 0; nt < 4; nt++)
        acc[mt][nt] = mfma16(af[mt], bfr[nt], acc[mt][nt]);
    if (kk < 15) writeX(vx, nxt);
    __syncthreads();
  }

  // epilogue: bias + fp16 + LDS transpose -> coalesced row stores
  u16* Tr = POOL;    // [r 128][o 128] fp16, o-chunk xor (r&7)
#pragma unroll
  for (int mt = 0; mt < 4; mt++)
#pragma unroll
    for (int nt = 0; nt < 4; nt++)
#pragma unroll
      for (int e = 0; e < 4; e++) {
        int o_g = osub + mt * 16 + lg * 4 + e;
        int r_g = rsub + nt * 16 + lr;
        float v = acc[mt][nt][e] + bias[o0 + o_g];
        Tr[r_g * 128 + (((o_g >> 3) ^ (r_g & 7)) << 3) + (o_g & 7)] = f2h(v);
      }
  __syncthreads();
  {
    int r_l = tid >> 1, half = tid & 1;
    int hh = r_l & 63, wl = r_l >> 6;
    size_t qrow = ((size_t)(b * 64 + hh) * 64 + (w0 + wl)) * 1024 + o0 + half * 64;
#pragma unroll
    for (int cc = 0; cc < 8; cc++) {
      int ob = half * 8 + cc;
      us8 v = *(const us8*)&Tr[r_l * 128 + ((ob ^ (r_l & 7)) << 3)];
      *(us8*)&qkv[qrow + cc * 8] = v;
    }
  }
}

// ---------- K2: attention per (slice s, head g). 4 waves, wave = 16 i-rows ----------
__global__ __launch_bounds__(256) void k2_attn(
    const u16* __restrict__ qkv, const u16* __restrict__ EqT,
    const u16* __restrict__ EkT, const u16* __restrict__ Evp,
    u16* __restrict__ attn)
{
  const int bid = blockIdx.x;
  const int s = bid >> 3, g = bid & 7;
  const int tid = threadIdx.x;
  const int l = tid & 63, wv = tid >> 6;
  const int lr = l & 15, lg = l >> 4;
  const int i0 = wv * 16;
  const u16* base = qkv + (size_t)s * 65536;

  __shared__ float QEt[128 * 68];   // [t][i] pad68 (scores in fp32)
  __shared__ float KEt[64 * 128];   // [j][t]
  u16* Pl  = (u16*)QEt;             // overlay after gather: [64][64] swizzled
  u16* VTl = (u16*)QEt + 4096;      // overlay: [c 64][j 64] swizzled

  // issue V loads early; held in regs through the MFMA phase
  us8 vreg0, vreg1;
  {
    int u0 = tid,        j0_ = u0 >> 3, cb0 = u0 & 7;
    int u1 = tid + 256,  j1_ = u1 >> 3, cb1 = u1 & 7;
    vreg0 = *(const us8*)(base + j0_ * 1024 + 512 + g * 64 + cb0 * 8);
    vreg1 = *(const us8*)(base + j1_ * 1024 + 512 + g * 64 + cb1 * 8);
  }

  // Q / K fragments (both natural [pos][chan] -> k-contiguous)
  h8v qf = *(const h8v*)(base + (i0 + lr) * 1024 + g * 32 + lg * 8);
  h8v kf[4];
#pragma unroll
  for (int jt = 0; jt < 4; jt++)
    kf[jt] = *(const h8v*)(base + (jt * 16 + lr) * 1024 + 256 + g * 32 + lg * 8);

  const f4v z4 = {0.f, 0.f, 0.f, 0.f};

  // QE[i][t] = Q^T @ Eq ; store transposed (lane regs are 4 consecutive i)
#pragma unroll
  for (int tt = 0; tt < 8; tt++) {
    h8v eb = *(const h8v*)(EqT + (tt * 16 + lr) * 32 + lg * 8);
    f4v d = mfma16(qf, eb, z4);
    *(f4v*)&QEt[(tt * 16 + lr) * 68 + i0 + lg * 4] = d;
  }
  // KET[t][j] = Ek^T @ K ; store as [j][t] (lane regs are 4 consecutive t)
#pragma unroll
  for (int q = 0; q < 2; q++) {
    int tt = wv * 2 + q;
    h8v ea = *(const h8v*)(EkT + (tt * 16 + lr) * 32 + lg * 8);
#pragma unroll
    for (int jt = 0; jt < 4; jt++) {
      f4v d = mfma16(ea, kf[jt], z4);
      *(f4v*)&KEt[(jt * 16 + lr) * 128 + tt * 16 + lg * 4] = d;
    }
  }
  // qk
  f4v sc[4];
#pragma unroll
  for (int jt = 0; jt < 4; jt++) sc[jt] = mfma16(qf, kf[jt], z4);

  __syncthreads();   // QEt/KEt visible

  // gather band terms + softmax over j (rows owned by this wave)
  float pv[4][4];    // [jt][r]
#pragma unroll
  for (int jt = 0; jt < 4; jt++)
#pragma unroll
    for (int r = 0; r < 4; r++) {
      int i = i0 + lg * 4 + r;
      int j = jt * 16 + lr;
      int tq = i - j + 63;
      pv[jt][r] = sc[jt][r] + QEt[tq * 68 + i] + KEt[j * 128 + (126 - tq)];
    }
  float rsum[4];
#pragma unroll
  for (int r = 0; r < 4; r++) {
    float m = fmaxf(fmaxf(pv[0][r], pv[1][r]), fmaxf(pv[2][r], pv[3][r]));
    m = fmaxf(m, __shfl_xor(m, 1));
    m = fmaxf(m, __shfl_xor(m, 2));
    m = fmaxf(m, __shfl_xor(m, 4));
    m = fmaxf(m, __shfl_xor(m, 8));
    float t0 = 0.f;
#pragma unroll
    for (int jt = 0; jt < 4; jt++) {
      pv[jt][r] = exp2f((pv[jt][r] - m) * 1.4426950408889634f);
      t0 += pv[jt][r];
    }
    t0 += __shfl_xor(t0, 1);
    t0 += __shfl_xor(t0, 2);
    t0 += __shfl_xor(t0, 4);
    t0 += __shfl_xor(t0, 8);
    rsum[r] = t0;
  }

  __syncthreads();   // all gathers done -> safe to overlay P/VT onto QEt

  // write P (unnormalized, fp16, j-chunk xor (i&7)) and VT from regs
#pragma unroll
  for (int jt = 0; jt < 4; jt++)
#pragma unroll
    for (int r = 0; r < 4; r++) {
      int i = i0 + lg * 4 + r;
      int j = jt * 16 + lr;
      Pl[i * 64 + (((j >> 3) ^ (i & 7)) << 3) + (j & 7)] = f2h(pv[jt][r]);
    }
  {
    int u0 = tid, j0_ = u0 >> 3, cb0 = u0 & 7;
#pragma unroll
    for (int e = 0; e < 8; e++) {
      int c = cb0 * 8 + e;
      VTl[c * 64 + (((j0_ >> 3) ^ (c & 7)) << 3) + (j0_ & 7)] = (u16)vreg0[e];
    }
    int u1 = tid + 256, j1_ = u1 >> 3, cb1 = u1 & 7;
#pragma unroll
    for (int e = 0; e < 8; e++) {
      int c = cb1 * 8 + e;
      VTl[c * 64 + (((j1_ >> 3) ^ (c & 7)) << 3) + (j1_ & 7)] = (u16)vreg1[e];
    }
  }
  __syncthreads();   // P / VT visible

  // PV + SVE accumulate into [i 16][c 64]
  f4v acc[4] = {z4, z4, z4, z4};
  {
    int i = i0 + lr;
#pragma unroll
    for (int kc = 0; kc < 2; kc++) {
      h8v pa = *(const h8v*)&Pl[i * 64 + (((kc * 4 + lg) ^ (i & 7)) << 3)];
#pragma unroll
      for (int ct = 0; ct < 4; ct++) {
        int cA = ct * 16 + lr;
        h8v vb = *(const h8v*)&VTl[cA * 64 + (((kc * 4 + lg) ^ (cA & 7)) << 3)];
        acc[ct] = mfma16(pa, vb, acc[ct]);
      }
    }
#pragma unroll
    for (int tc = 0; tc < 4; tc++) {
      h8v pa;
#pragma unroll
      for (int e = 0; e < 8; e++) {
        int t = tc * 32 + lg * 8 + e;
        int j = i + 63 - t;
        int jc = j < 0 ? 0 : (j > 63 ? 63 : j);
        u16 tmp = Pl[i * 64 + (((jc >> 3) ^ (i & 7)) << 3) + (jc & 7)];
        pa[e] = (j >= 0 && j < 64) ? bits2h(tmp) : (_Float16)0.f;
      }
#pragma unroll
      for (int ct = 0; ct < 4; ct++) {
        h8v eb = *(const h8v*)(Evp + (ct * 16 + lr) * 128 + tc * 32 + lg * 8);
        acc[ct] = mfma16(pa, eb, acc[ct]);
      }
    }
  }
  // normalize + store attn rows [s*64+i][g*64+c]
  float inv[4];
#pragma unroll
  for (int r = 0; r < 4; r++) inv[r] = 1.f / rsum[r];
#pragma unroll
  for (int ct = 0; ct < 4; ct++)
#pragma unroll
    for (int r = 0; r < 4; r++) {
      int i = i0 + lg * 4 + r;
      attn[(size_t)(s * 64 + i) * 512 + g * 64 + ct * 16 + lr] =
          f2h(acc[ct][r] * inv[r]);
    }
}

// ---------- K3: out = attn @ Wout^T + b, D[m=o][n=h] -> coalesced h stores ----------
__global__ __launch_bounds__(512) void k3_oproj(
    const u16* __restrict__ attn, const u16* __restrict__ Woutb,
    const float* __restrict__ ob, float* __restrict__ out)
{
  const int bid = blockIdx.x;
  const int b = bid >> 6, w = bid & 63;
  const int tid = threadIdx.x;
  const int l = tid & 63, wv = tid >> 6;   // 8 waves, wave = 64 o-rows
  const int lr = l & 15, lg = l >> 4;

  __shared__ u16 Bl[2][64 * 64];   // attn rows, C-chunk xor (h&7)

  f4v acc[4][4];
#pragma unroll
  for (int a_ = 0; a_ < 4; a_++)
#pragma unroll
    for (int b_ = 0; b_ < 4; b_++) acc[a_][b_] = (f4v){0.f, 0.f, 0.f, 0.f};

  auto stageB = [&](int kk, int buf) {
    int c0 = kk * 64;
    int h_l = wv * 8 + (l >> 3);
    int p = l & 7;
    const u16* src = attn + ((size_t)b * 4096 + (size_t)h_l * 64 + w) * 512 + c0 +
                     ((p ^ (h_l & 7)) << 3);
    gll16(src, &Bl[buf][wv * 512]);
  };

  stageB(0, 0);
  __syncthreads();

  for (int kk = 0; kk < 8; kk++) {
    int cur = kk & 1, nxt = cur ^ 1;
    if (kk < 7) stageB(kk + 1, nxt);
    int c0 = kk * 64;
    h8v af[4][2], bf[4][2];
#pragma unroll
    for (int mt = 0; mt < 4; mt++)
#pragma unroll
      for (int kc = 0; kc < 2; kc++)
        af[mt][kc] = *(const h8v*)(Woutb + (size_t)(wv * 64 + mt * 16 + lr) * 512 +
                                   c0 + kc * 32 + lg * 8);
#pragma unroll
    for (int jt = 0; jt < 4; jt++)
#pragma unroll
      for (int kc = 0; kc < 2; kc++) {
        int h = jt * 16 + lr;
        bf[jt][kc] = *(const h8v*)&Bl[cur][h * 64 + (((kc * 4 + lg) ^ (h & 7)) << 3)];
      }
#pragma unroll
    for (int mt = 0; mt < 4; mt++)
#pragma unroll
      for (int jt = 0; jt < 4; jt++)
#pragma unroll
        for (int kc = 0; kc < 2; kc++)
          acc[mt][jt] = mfma16(af[mt][kc], bf[jt][kc], acc[mt][jt]);
    __syncthreads();
  }

#pragma unroll
  for (int mt = 0; mt < 4; mt++)
#pragma unroll
    for (int jt = 0; jt < 4; jt++)
#pragma unroll
      for (int e = 0; e < 4; e++) {
        int o = wv * 64 + mt * 16 + lg * 4 + e;
        int h = jt * 16 + lr;
        out[(((size_t)b * 512 + o) * 64 + w) * 64 + h] = acc[mt][jt][e] + ob[o];
      }
}

// ---------- launch ----------
extern "C" void kernel_launch(void* const* d_in, const int* in_sizes, int n_in,
                              void* d_out, int out_size, void* d_ws, size_t ws_size,
                              hipStream_t stream)
{
  (void)in_sizes; (void)n_in; (void)out_size; (void)ws_size;
  const float* x    = (const float*)d_in[0];
  const float* w1   = (const float*)d_in[1];
  const float* b1   = (const float*)d_in[2];
  const float* wout = (const float*)d_in[3];
  const float* bo   = (const float*)d_in[4];
  const float* rel  = (const float*)d_in[5];
  float* out = (float*)d_out;

  char* ws = (char*)d_ws;                       // needs ~193.6 MiB
  u16* qkv_ws  = (u16*)ws;                      // 134,217,728 B
  u16* attn_ws = (u16*)(ws + 134217728);        //  67,108,864 B
  u16* W1b     = (u16*)(ws + 201326592);        //   1,048,576 B
  u16* Woutb   = (u16*)(ws + 202375168);        //     524,288 B
  u16* EqT     = (u16*)(ws + 202899456);        //       8,192 B
  u16* EkT     = (u16*)(ws + 202907648);        //       8,192 B
  u16* Evp     = (u16*)(ws + 202915840);        //      16,384 B

  k0_setup<<<dim3(3136), dim3(256), 0, stream>>>(w1, wout, rel, W1b, Woutb, EqT, EkT, Evp);
  k1_qkv  <<<dim3(4096), dim3(256), 0, stream>>>(x, W1b, b1, qkv_ws);
  k2_attn <<<dim3(8192), dim3(256), 0, stream>>>(qkv_ws, EqT, EkT, Evp, attn_ws);
  k3_oproj<<<dim3(1024), dim3(512), 0, stream>>>(attn_ws, Woutb, bo, out);
}